// Round 3
// baseline (267.054 us; speedup 1.0000x reference)
//
#include <hip/hip_runtime.h>

#define B_ 8
#define L_ 4096
#define H_ 8
#define E_ 64
#define NEIGH_ 128
#define NJ 4          // j-splits per block
#define BQ 128
#define KROW 72       // shorts per K row (64 + 8 pad)
#define HE 512        // H_*E_

typedef float f32x4 __attribute__((ext_vector_type(4)));
typedef __bf16 bf16x8 __attribute__((ext_vector_type(8)));
typedef unsigned short u16x4 __attribute__((ext_vector_type(4)));
typedef unsigned short u16x8 __attribute__((ext_vector_type(8)));
typedef unsigned int u32;

__device__ inline unsigned short f2bf(float f) {
  return __builtin_bit_cast(unsigned short, (__bf16)f);   // lets compiler pack v_cvt_pk_bf16_f32
}
__device__ inline u32 pack2(float a, float b) {
  return (u32)f2bf(a) | ((u32)f2bf(b) << 16);
}
__device__ inline int vsig(int e) {   // V granule swizzle: free writes AND balanced reads
  return ((e & 15) ^ ((e >> 2) & 7)) & 7;
}

__global__ __launch_bounds__(512, 4) void la_kernel(
    const float* __restrict__ Q, const float* __restrict__ K,
    const float* __restrict__ V, float* __restrict__ out) {
  const int jg = blockIdx.x, h = blockIdx.y, b = blockIdx.z;
  const int t = threadIdx.x;

  __shared__ unsigned short Ks[2][BQ * KROW];  // 36,864 B
  __shared__ u32 Vs[2][E_ * 64];               // 32,768 B (VsT, granule-swizzled, no pad)

  const size_t bh = (size_t)b * (L_ * HE) + h * E_;
  const float* Qp = Q + bh;
  const float* Kp = K + bh;
  const float* Vp = V + bh;
  float* Op = out + bh;

  const int base = jg * (NJ * BQ);
  const int wv = t >> 6, lane = t & 63;
  const int l15 = lane & 15, quad = lane >> 4;
  const int r0 = wv * 16;
  const int lq = r0 + l15;     // this lane's query (local 0..127)

  // ---------- prologue: buf1 <- keys [base-128, base), buf0 <- [base, base+128) ----------
  for (int half = 0; half < 2; ++half) {
    const int buf = 1 - half;
    const int gs = base - NEIGH_ + half * NEIGH_;
    for (int i = 0; i < 4; ++i) {            // K: 128 rows x 16 float4
      int idx = t + i * 512;
      int row = idx >> 4, c4 = idx & 15;
      int g = gs + row; g = g < 0 ? 0 : g;
      const float4 v = *(const float4*)(Kp + (size_t)g * HE + c4 * 4);
      *(u16x4*)&Ks[buf][row * KROW + c4 * 4] =
          (u16x4){f2bf(v.x), f2bf(v.y), f2bf(v.z), f2bf(v.w)};
    }
    for (int i = 0; i < 2; ++i) {            // V: 64 key-pairs x 16 float4-cols
      int idx = t + i * 512;
      int kp = idx >> 4, c4 = idx & 15;
      int ga = gs + 2 * kp, gb = ga + 1;
      ga = ga < 0 ? 0 : ga; gb = gb < 0 ? 0 : gb;
      const float4 va = *(const float4*)(Vp + (size_t)ga * HE + c4 * 4);
      const float4 vb = *(const float4*)(Vp + (size_t)gb * HE + c4 * 4);
      const float fa[4] = {va.x, va.y, va.z, va.w};
      const float fb[4] = {vb.x, vb.y, vb.z, vb.w};
      int g4 = kp >> 2, ko = kp & 3;
#pragma unroll
      for (int w = 0; w < 4; ++w) {
        int e = c4 * 4 + w;
        Vs[buf][e * 64 + (((g4 ^ vsig(e)) << 2) | ko)] = pack2(fa[w], fb[w]);
      }
    }
  }
  __syncthreads();

  for (int j = 0; j < NJ; ++j) {
    const int q0 = base + j * BQ;
    const int g0 = q0 - NEIGH_;
    const int lob = (j + 1) & 1, hib = j & 1;   // lo half in lob, hi half in hib
    const bool pf = (j + 1 < NJ);
    const int gn = q0 + BQ;                     // next iter's new (high) half

    // ---- Q fragment (per-lane, global) ----
    bf16x8 qfrag[2];
    {
      const float* qrow = Qp + (size_t)(q0 + lq) * HE;
#pragma unroll
      for (int ks = 0; ks < 2; ++ks) {
        const float4 x = *(const float4*)(qrow + ks * 32 + quad * 8);
        const float4 y = *(const float4*)(qrow + ks * 32 + quad * 8 + 4);
        qfrag[ks] = __builtin_bit_cast(bf16x8,
            (u16x8){f2bf(x.x), f2bf(x.y), f2bf(x.z), f2bf(x.w),
                    f2bf(y.x), f2bf(y.y), f2bf(y.z), f2bf(y.w)});
      }
    }

    // ---- prefetch next K half (issued before QK; consumed after PV barrier) ----
    float4 nK[4];
    if (pf) {
#pragma unroll
      for (int i = 0; i < 4; ++i) {
        int idx = t + i * 512;
        int row = idx >> 4, c4 = idx & 15;
        nK[i] = *(const float4*)(Kp + (size_t)(gn + row) * HE + c4 * 4);
      }
    }

    // ---- S^T = K Q^T ----
    f32x4 S[16];
#pragma unroll
    for (int kt = 0; kt < 16; ++kt) S[kt] = (f32x4){0.f, 0.f, 0.f, 0.f};
#pragma unroll
    for (int ks = 0; ks < 2; ++ks) {
#pragma unroll
      for (int kt = 0; kt < 16; ++kt) {
        const unsigned short* kb = (kt < 8)
            ? &Ks[lob][(kt * 16 + l15) * KROW]
            : &Ks[hib][((kt - 8) * 16 + l15) * KROW];
        bf16x8 a = __builtin_bit_cast(bf16x8, *(const u16x8*)(kb + ks * 32 + quad * 8));
        S[kt] = __builtin_amdgcn_mfma_f32_16x16x32_bf16(a, qfrag[ks], S[kt], 0, 0, 0);
      }
    }

    // ---- scale + mask + row max (lane owns query q=l15 of its wave tile) ----
    float m = -1e30f;
#pragma unroll
    for (int kt = 0; kt < 16; ++kt) {
#pragma unroll
      for (int r = 0; r < 4; ++r) {
        int key = kt * 16 + quad * 4 + r;
        float s = S[kt][r] * 0.125f;
        bool valid = (key > lq) & (key <= lq + NEIGH_) & (g0 + key >= 0);
        s = valid ? s : -1e30f;
        S[kt][r] = s;
        m = fmaxf(m, s);
      }
    }
    m = fmaxf(m, __shfl_xor(m, 16));
    m = fmaxf(m, __shfl_xor(m, 32));

    // ---- exp + row sum; pack P (C-layout regs (0,1),(2,3)) ----
    float lsum = 0.f;
    u32 pk[16][2];
#pragma unroll
    for (int kt = 0; kt < 16; ++kt) {
      float p0 = __expf(S[kt][0] - m);
      float p1 = __expf(S[kt][1] - m);
      float p2 = __expf(S[kt][2] - m);
      float p3 = __expf(S[kt][3] - m);
      lsum += (p0 + p1) + (p2 + p3);
      pk[kt][0] = pack2(p0, p1);
      pk[kt][1] = pack2(p2, p3);
    }
    lsum += __shfl_xor(lsum, 16);
    lsum += __shfl_xor(lsum, 32);
    const float inv = 1.0f / lsum;

    // ---- prefetch next V half ----
    float4 nV[4];
    if (pf) {
#pragma unroll
      for (int i = 0; i < 2; ++i) {
        int idx = t + i * 512;
        int kp = idx >> 4, c4 = idx & 15;
        nV[2 * i]     = *(const float4*)(Vp + (size_t)(gn + 2 * kp) * HE + c4 * 4);
        nV[2 * i + 1] = *(const float4*)(Vp + (size_t)(gn + 2 * kp + 1) * HE + c4 * 4);
      }
    }

    // ---- O = P V : register transpose of P, swizzled VsT b128 reads ----
    f32x4 O[4];
#pragma unroll
    for (int et = 0; et < 4; ++et) O[et] = (f32x4){0.f, 0.f, 0.f, 0.f};
    int vbase[4], sig[4];
#pragma unroll
    for (int et = 0; et < 4; ++et) {
      int e = et * 16 + l15;
      vbase[et] = e * 64;
      sig[et] = vsig(e);
    }
    const int srcBase = 16 * ((quad & 1) * 2) + l15;
    const bool hiTile = (quad >> 1) != 0;
#pragma unroll
    for (int ks = 0; ks < 8; ++ks) {
      u32 a32[4];
#pragma unroll
      for (int k = 0; k < 4; ++k) {
        int src = srcBase + 16 * (k >> 1);
        u32 u0 = (u32)__shfl((int)pk[2 * ks][k & 1], src);
        u32 u1 = (u32)__shfl((int)pk[2 * ks + 1][k & 1], src);
        a32[k] = hiTile ? u1 : u0;
      }
      bf16x8 afrag = __builtin_bit_cast(bf16x8,
          (u32 __attribute__((ext_vector_type(4)))){a32[0], a32[1], a32[2], a32[3]});
      const u32* vb = (ks < 4) ? &Vs[lob][0] : &Vs[hib][0];
      const int ks4 = ks & 3;
#pragma unroll
      for (int et = 0; et < 4; ++et) {
        int word = vbase[et] + ((((ks4 * 4 + quad) ^ sig[et])) << 2);
        bf16x8 bfrag = __builtin_bit_cast(bf16x8, *(const u16x8*)((const unsigned short*)(vb + word)));
        O[et] = __builtin_amdgcn_mfma_f32_16x16x32_bf16(afrag, bfrag, O[et], 0, 0, 0);
      }
    }

    // ---- store ----
    float invq[4];
#pragma unroll
    for (int r = 0; r < 4; ++r) invq[r] = __shfl(inv, quad * 4 + r);
#pragma unroll
    for (int et = 0; et < 4; ++et)
#pragma unroll
      for (int r = 0; r < 4; ++r) {
        int row = r0 + quad * 4 + r;
        Op[(size_t)(q0 + row) * HE + et * 16 + l15] = O[et][r] * invq[r];
      }

    // ---- stage prefetched half into the (now free) low buffer ----
    if (pf) {
      __syncthreads();
#pragma unroll
      for (int i = 0; i < 4; ++i) {
        int idx = t + i * 512;
        int row = idx >> 4, c4 = idx & 15;
        *(u16x4*)&Ks[lob][row * KROW + c4 * 4] =
            (u16x4){f2bf(nK[i].x), f2bf(nK[i].y), f2bf(nK[i].z), f2bf(nK[i].w)};
      }
#pragma unroll
      for (int i = 0; i < 2; ++i) {
        int idx = t + i * 512;
        int kp = idx >> 4, c4 = idx & 15;
        const float4 va = nV[2 * i], vb2 = nV[2 * i + 1];
        const float fa[4] = {va.x, va.y, va.z, va.w};
        const float fb[4] = {vb2.x, vb2.y, vb2.z, vb2.w};
        int g4 = kp >> 2, ko = kp & 3;
#pragma unroll
        for (int w = 0; w < 4; ++w) {
          int e = c4 * 4 + w;
          Vs[lob][e * 64 + (((g4 ^ vsig(e)) << 2) | ko)] = pack2(fa[w], fb[w]);
        }
      }
      __syncthreads();
    }
  }
}

extern "C" void kernel_launch(void* const* d_in, const int* in_sizes, int n_in,
                              void* d_out, int out_size, void* d_ws, size_t ws_size,
                              hipStream_t stream) {
  const float* q = (const float*)d_in[0];
  const float* k = (const float*)d_in[1];
  const float* v = (const float*)d_in[2];
  float* o = (float*)d_out;
  dim3 grid(L_ / (NJ * BQ), H_, B_);   // 8 x 8 x 8 = 512 blocks = 2/CU
  la_kernel<<<grid, 512, 0, stream>>>(q, k, v, o);
}